// Round 8
// baseline (367.427 us; speedup 1.0000x reference)
//
#include <hip/hip_runtime.h>
#include <hip/hip_bf16.h>

// GConvGRU (ChebConv K=2), fp32 in/out; bf16 MFMA GEMM; fp8 gather path.
// Zin row K-layout: [x | hx | px | ph] (512 bf16 = 1 KB/node).
// xf8[n]: 256 fp8 bytes = concat(x[n],hx[n]) * norm[n]  (prescaled).
// Pipeline: memset -> count(binned LDS hist, nt reads) -> scanA/B/C
//           -> convert(bf16+fp8) -> prep -> fill(binned, nt reads) -> agg(fp8)
//           -> gemm -> epilogue

typedef unsigned short u16;
typedef unsigned int u32;
typedef __attribute__((ext_vector_type(8))) __bf16 bf16x8;
typedef __attribute__((ext_vector_type(4))) float f32x4;
typedef __attribute__((ext_vector_type(2))) float f32x2;
typedef __attribute__((ext_vector_type(4))) int int4v;

#define F_IN 128
#define HID 128

__device__ __forceinline__ u16 f2bf(float f) {
    u32 u;
    __builtin_memcpy(&u, &f, 4);
    u = (u + 0x7fffu + ((u >> 16) & 1u)) >> 16;
    return (u16)u;
}
__device__ __forceinline__ float bflo(u32 w) {
    u32 u = w << 16;
    float f;
    __builtin_memcpy(&f, &u, 4);
    return f;
}
__device__ __forceinline__ float bfhi(u32 w) {
    u32 u = w & 0xffff0000u;
    float f;
    __builtin_memcpy(&f, &u, 4);
    return f;
}
__device__ __forceinline__ u32 packbf(float a, float b) {
    return ((u32)f2bf(b) << 16) | (u32)f2bf(a);
}
__device__ __forceinline__ float sigmoidf_(float x) {
    return 1.0f / (1.0f + __expf(-x));
}

__device__ __forceinline__ void async_copy16(void* lds, const void* gptr) {
    __builtin_amdgcn_global_load_lds(
        (__attribute__((address_space(1))) void*)gptr,
        (__attribute__((address_space(3))) void*)lds,
        16, 0, 0);
}

// ------------- 1. degree count: binned LDS histogram, nt edge reads -------------
__global__ __launch_bounds__(256) void count_kernel(const int* __restrict__ dst, int E,
                                                    int* __restrict__ counts,
                                                    int nodesPerRange, int edgesPerChunk,
                                                    int N) {
    extern __shared__ int hist[];
    int range = blockIdx.x & 7;
    int chunk = blockIdx.x >> 3;
    int lo = range * nodesPerRange;
    int hiN = N - lo;
    int npr = nodesPerRange < hiN ? nodesPerRange : hiN;
    for (int j = threadIdx.x; j < npr; j += 256) hist[j] = 0;
    __syncthreads();
    int beg = chunk * edgesPerChunk;
    int end = beg + edgesPerChunk;
    if (end > E) end = E;
    for (int i = beg + (int)threadIdx.x * 4; i < end; i += 256 * 4) {
        if (i + 4 <= end) {
            int4v d4 = __builtin_nontemporal_load((const int4v*)(dst + i));
#pragma unroll
            for (int j = 0; j < 4; ++j) {
                unsigned r = (unsigned)(d4[j] - lo);
                if (r < (unsigned)npr) atomicAdd(&hist[r], 1);
            }
        } else {
            for (int j = i; j < end; ++j) {
                unsigned r = (unsigned)(dst[j] - lo);
                if (r < (unsigned)npr) atomicAdd(&hist[r], 1);
            }
        }
    }
    __syncthreads();
    for (int j = threadIdx.x; j < npr; j += 256) {
        int v = hist[j];
        if (v) atomicAdd(&counts[lo + j], v);
    }
}

// ------------- 2a. block-level scan (coalesced) -------------
__global__ __launch_bounds__(1024) void scanA_kernel(const int* __restrict__ counts,
                                                     int* __restrict__ pre,
                                                     int* __restrict__ partials, int N) {
    __shared__ int buf[1024];
    int tid = threadIdx.x;
    int t = blockIdx.x * 1024 + tid;
    int v = (t < N) ? counts[t] : 0;
    buf[tid] = v;
    __syncthreads();
    for (int off = 1; off < 1024; off <<= 1) {
        int o = (tid >= off) ? buf[tid - off] : 0;
        __syncthreads();
        buf[tid] += o;
        __syncthreads();
    }
    if (t < N) pre[t] = buf[tid] - v;
    if (tid == 1023) partials[blockIdx.x] = buf[1023];
}

// ------------- 2b. scan the block totals (1 block) -------------
__global__ __launch_bounds__(1024) void scanB_kernel(int* __restrict__ partials, int NB) {
    __shared__ int buf[1024];
    int tid = threadIdx.x;
    int v = (tid < NB) ? partials[tid] : 0;
    buf[tid] = v;
    __syncthreads();
    for (int off = 1; off < 1024; off <<= 1) {
        int o = (tid >= off) ? buf[tid - off] : 0;
        __syncthreads();
        buf[tid] += o;
        __syncthreads();
    }
    if (tid < NB) partials[tid] = buf[tid] - v;
}

// ------------- 2c. combine + norm (coalesced) -------------
__global__ void scanC_kernel(const int* __restrict__ counts, const int* __restrict__ pre,
                             const int* __restrict__ partials, int* __restrict__ row_ptr,
                             int* __restrict__ cursor, float* __restrict__ norm, int N, int E) {
    int i = blockIdx.x * blockDim.x + threadIdx.x;
    if (i < N) {
        int r = pre[i] + partials[i >> 10];
        row_ptr[i] = r;
        cursor[i] = r;
        int c = counts[i];
        norm[i] = rsqrtf((float)(c > 1 ? c : 1));
    }
    if (i == 0) row_ptr[N] = E;
}

// ------------- 3. convert: x,hx -> Zin bf16 slots + prescaled fp8 rows -------------
__global__ void convert_kernel(const float* __restrict__ x, const float* __restrict__ hx,
                               const float* __restrict__ norm,
                               u32* __restrict__ zin, u32* __restrict__ xf8, int N) {
    int t = blockIdx.x * blockDim.x + threadIdx.x;
    if (t >= N * 64) return;
    int n = t >> 6, c4 = t & 63;
    float4 v;
    int zbase;
    if (c4 < 32) {
        v = ((const float4*)x)[n * 32 + c4];
        zbase = n * 256 + 2 * c4;
    } else {
        v = ((const float4*)hx)[n * 32 + (c4 - 32)];
        zbase = n * 256 + 64 + 2 * (c4 - 32);
    }
    zin[zbase] = packbf(v.x, v.y);
    zin[zbase + 1] = packbf(v.z, v.w);
    float ns = norm[n];
    u32 o = 0;
    o = (u32)__builtin_amdgcn_cvt_pk_fp8_f32(v.x * ns, v.y * ns, (int)o, false);
    o = (u32)__builtin_amdgcn_cvt_pk_fp8_f32(v.z * ns, v.w * ns, (int)o, true);
    xf8[t] = o;
}

// ------------- 4. weight prepack (fp32 -> bf16) + bias pack -------------
__global__ void prep_kernel(const float* __restrict__ Wrx, const float* __restrict__ Wrh,
                            const float* __restrict__ Wux, const float* __restrict__ Wuh,
                            const float* __restrict__ Wcx, const float* __restrict__ Wch,
                            const float* __restrict__ brx, const float* __restrict__ brh,
                            const float* __restrict__ bux, const float* __restrict__ buh,
                            const float* __restrict__ bcx, const float* __restrict__ bch,
                            u16* __restrict__ WT, float* __restrict__ bias) {
    int t = blockIdx.x * blockDim.x + threadIdx.x;  // [0, 512*512)
    int c = t >> 9, k = t & 511;
    int part = c >> 7, c0 = c & 127;
    int kpart = k >> 7;
    int kf = k & 127;
    int t01 = (kpart & 2) ? 1 : 0;
    bool isX = !(kpart & 1);
    int wi = t01 * (128 * 128) + kf * 128 + c0;
    float val = 0.0f;
    if (part == 0) val = isX ? Wrx[wi] : Wrh[wi];
    else if (part == 1) val = isX ? Wux[wi] : Wuh[wi];
    else if (part == 2) { if (isX) val = Wcx[wi]; }
    else { if (!isX) val = Wch[wi]; }
    WT[c * 512 + k] = f2bf(val);
    if (t < 512) {
        int bp = t >> 7, bc = t & 127;
        float b = 0.0f;
        if (bp == 0) b = brx[bc] + brh[bc];
        else if (bp == 1) b = bux[bc] + buh[bc];
        else if (bp == 2) b = bcx[bc];
        else b = bch[bc];
        bias[t] = b;
    }
}

// ------------- 5. CSR fill: binned, nt dst stream, conditional src load -------------
__global__ __launch_bounds__(256) void fill_kernel(const int* __restrict__ src,
                                                   const int* __restrict__ dst, int E,
                                                   int* __restrict__ cursor,
                                                   int* __restrict__ esrc,
                                                   int nodesPerRange, int edgesPerChunk) {
    int range = blockIdx.x & 7;
    int chunk = blockIdx.x >> 3;
    int lo = range * nodesPerRange;
    int beg = chunk * edgesPerChunk;
    int end = beg + edgesPerChunk;
    if (end > E) end = E;
    for (int i = beg + (int)threadIdx.x * 4; i < end; i += 256 * 4) {
        if (i + 4 <= end) {
            int4v d4 = __builtin_nontemporal_load((const int4v*)(dst + i));
#pragma unroll
            for (int j = 0; j < 4; ++j) {
                int d = d4[j];
                if ((unsigned)(d - lo) < (unsigned)nodesPerRange) {
                    int s = src[i + j];          // sparse (1/8) scalar load
                    int slot = atomicAdd(&cursor[d], 1);
                    esrc[slot] = s;
                }
            }
        } else {
            for (int j = i; j < end; ++j) {
                int d = dst[j];
                if ((unsigned)(d - lo) < (unsigned)nodesPerRange) {
                    int slot = atomicAdd(&cursor[d], 1);
                    esrc[slot] = src[j];
                }
            }
        }
    }
}

// ------------- 6. wave-per-node fp8 gather-aggregate, 8 edges/iter -------------
__global__ __launch_bounds__(256) void agg_kernel(const int* __restrict__ row_ptr,
                                                  const int* __restrict__ esrc,
                                                  const float* __restrict__ norm,
                                                  const u32* __restrict__ xf8,
                                                  u32* __restrict__ zin, int N) {
    int node = blockIdx.x * 4 + (threadIdx.x >> 6);
    int lane = threadIdx.x & 63;
    if (node >= N) return;
    int q = lane >> 4;
    int li = lane & 15;
    int beg = row_ptr[node], end = row_ptr[node + 1];
    const uint4* z4 = (const uint4*)xf8;
    f32x2 acc[8];
#pragma unroll
    for (int i = 0; i < 8; ++i) acc[i] = (f32x2){0.f, 0.f};

    int nE = end - beg;
    int mainEnd = beg + (nE & ~7);
    int e = beg;
    if (e < mainEnd) {
        int sA = esrc[e + q];
        int sB = esrc[e + q + 4];
        for (;;) {
            uint4 vA = z4[(size_t)sA * 16 + li];
            uint4 vB = z4[(size_t)sB * 16 + li];
            e += 8;
            bool more = e < mainEnd;
            int tA = 0, tB = 0;
            if (more) {
                tA = esrc[e + q];
                tB = esrc[e + q + 4];
            }
#pragma unroll
            for (int i = 0; i < 4; ++i) {
                u32 w = (i == 0) ? vA.x : (i == 1) ? vA.y : (i == 2) ? vA.z : vA.w;
                acc[2 * i] += (f32x2)__builtin_amdgcn_cvt_pk_f32_fp8((int)w, false);
                acc[2 * i + 1] += (f32x2)__builtin_amdgcn_cvt_pk_f32_fp8((int)w, true);
            }
#pragma unroll
            for (int i = 0; i < 4; ++i) {
                u32 w = (i == 0) ? vB.x : (i == 1) ? vB.y : (i == 2) ? vB.z : vB.w;
                acc[2 * i] += (f32x2)__builtin_amdgcn_cvt_pk_f32_fp8((int)w, false);
                acc[2 * i + 1] += (f32x2)__builtin_amdgcn_cvt_pk_f32_fp8((int)w, true);
            }
            if (!more) break;
            sA = tA;
            sB = tB;
        }
    }
    for (int t = mainEnd + q; t < end; t += 4) {
        int s = esrc[t];
        uint4 v = z4[(size_t)s * 16 + li];
#pragma unroll
        for (int i = 0; i < 4; ++i) {
            u32 w = (i == 0) ? v.x : (i == 1) ? v.y : (i == 2) ? v.z : v.w;
            acc[2 * i] += (f32x2)__builtin_amdgcn_cvt_pk_f32_fp8((int)w, false);
            acc[2 * i + 1] += (f32x2)__builtin_amdgcn_cvt_pk_f32_fp8((int)w, true);
        }
    }
#pragma unroll
    for (int i = 0; i < 8; ++i) {
        acc[i].x += __shfl_xor(acc[i].x, 16);
        acc[i].y += __shfl_xor(acc[i].y, 16);
        acc[i].x += __shfl_xor(acc[i].x, 32);
        acc[i].y += __shfl_xor(acc[i].y, 32);
    }
    if (lane < 16) {
        float nn = -norm[node];
        uint4 o0, o1;
        o0.x = packbf(acc[0].x * nn, acc[0].y * nn);
        o0.y = packbf(acc[1].x * nn, acc[1].y * nn);
        o0.z = packbf(acc[2].x * nn, acc[2].y * nn);
        o0.w = packbf(acc[3].x * nn, acc[3].y * nn);
        o1.x = packbf(acc[4].x * nn, acc[4].y * nn);
        o1.y = packbf(acc[5].x * nn, acc[5].y * nn);
        o1.z = packbf(acc[6].x * nn, acc[6].y * nn);
        o1.w = packbf(acc[7].x * nn, acc[7].y * nn);
        uint4* dst4 = (uint4*)zin + (size_t)node * 64 + 32 + li * 2;
        dst4[0] = o0;
        dst4[1] = o1;
    }
}

// ------------- 7. MFMA GEMM: Z[M,512] = A[M,512] * B^T (B stored [col][k]) -------------
__global__ __launch_bounds__(256) void gemm_kernel(const u16* __restrict__ A,
                                                   const u16* __restrict__ B,
                                                   u16* __restrict__ C, int M) {
    __shared__ __align__(16) __bf16 As[128 * 32];
    __shared__ __align__(16) __bf16 Bs[128 * 32];
    int tid = threadIdx.x;
    int wave = tid >> 6, lane = tid & 63;
    int m0 = blockIdx.x * 128;
    int n0 = blockIdx.y * 128;
    int wm = wave & 1, wn = wave >> 1;
    int quad = lane >> 4, l15 = lane & 15;

    f32x4 acc[4][4];
#pragma unroll
    for (int mi = 0; mi < 4; ++mi)
#pragma unroll
        for (int ni = 0; ni < 4; ++ni) acc[mi][ni] = (f32x4){0.f, 0.f, 0.f, 0.f};

    for (int k0 = 0; k0 < 512; k0 += 32) {
        __syncthreads();
#pragma unroll
        for (int j = 0; j < 2; ++j) {
            int chunk = wave * 2 + j;
            int fl = chunk * 512 + lane * 8;
            int row = fl >> 5;
            int col = fl & 31;
            async_copy16(&As[chunk * 512], A + (size_t)(m0 + row) * 512 + k0 + col);
            async_copy16(&Bs[chunk * 512], B + (size_t)(n0 + row) * 512 + k0 + col);
        }
        __syncthreads();
        bf16x8 af[4], bfr[4];
#pragma unroll
        for (int mi = 0; mi < 4; ++mi)
            af[mi] = *(const bf16x8*)&As[(wm * 64 + mi * 16 + l15) * 32 + quad * 8];
#pragma unroll
        for (int ni = 0; ni < 4; ++ni)
            bfr[ni] = *(const bf16x8*)&Bs[(wn * 64 + ni * 16 + l15) * 32 + quad * 8];
#pragma unroll
        for (int mi = 0; mi < 4; ++mi)
#pragma unroll
            for (int ni = 0; ni < 4; ++ni)
                acc[mi][ni] = __builtin_amdgcn_mfma_f32_16x16x32_bf16(af[mi], bfr[ni],
                                                                      acc[mi][ni], 0, 0, 0);
    }
#pragma unroll
    for (int mi = 0; mi < 4; ++mi)
#pragma unroll
        for (int ni = 0; ni < 4; ++ni)
#pragma unroll
            for (int r = 0; r < 4; ++r) {
                int row = m0 + wm * 64 + mi * 16 + quad * 4 + r;
                int col = n0 + wn * 64 + ni * 16 + l15;
                C[(size_t)row * 512 + col] = f2bf(acc[mi][ni][r]);
            }
}

// ------------- 8. gate epilogue (fp32 out), 2 features/thread -------------
__global__ void epilogue_kernel(const u32* __restrict__ Z, const float* __restrict__ bias,
                                const float* __restrict__ hx, float* __restrict__ out, int N) {
    int t = blockIdx.x * blockDim.x + threadIdx.x;
    if (t >= N * 64) return;
    int n = t >> 6, l = t & 63;
    const u32* z = Z + (size_t)n * 256;
    const float2* b2 = (const float2*)bias;
    u32 wr = z[l], wu = z[64 + l], wcx = z[128 + l], wch = z[192 + l];
    float2 br = b2[l], bu = b2[64 + l], bcx = b2[128 + l], bch = b2[192 + l];
    float2 h = ((const float2*)hx)[t];
    float r0 = sigmoidf_(bflo(wr) + br.x);
    float r1 = sigmoidf_(bfhi(wr) + br.y);
    float u0 = sigmoidf_(bflo(wu) + bu.x);
    float u1 = sigmoidf_(bfhi(wu) + bu.y);
    float c0 = sigmoidf_((bflo(wcx) + bcx.x) + (bflo(wch) + bch.x) * r0);
    float c1 = sigmoidf_((bfhi(wcx) + bcx.y) + (bfhi(wch) + bch.y) * r1);
    float2 o;
    o.x = u0 * h.x + (1.0f - u0) * c0;
    o.y = u1 * h.y + (1.0f - u1) * c1;
    ((float2*)out)[t] = o;
}

extern "C" void kernel_launch(void* const* d_in, const int* in_sizes, int n_in,
                              void* d_out, int out_size, void* d_ws, size_t ws_size,
                              hipStream_t stream) {
    const int* ei = (const int*)d_in[0];
    int E = in_sizes[0] / 2;
    const float* x = (const float*)d_in[1];
    const float* hx = (const float*)d_in[2];
    int N = in_sizes[1] / F_IN;
    const float* Wrx = (const float*)d_in[3];
    const float* brx = (const float*)d_in[4];
    const float* Wrh = (const float*)d_in[5];
    const float* brh = (const float*)d_in[6];
    const float* Wux = (const float*)d_in[7];
    const float* bux = (const float*)d_in[8];
    const float* Wuh = (const float*)d_in[9];
    const float* buh = (const float*)d_in[10];
    const float* Wcx = (const float*)d_in[11];
    const float* bcx = (const float*)d_in[12];
    const float* Wch = (const float*)d_in[13];
    const float* bch = (const float*)d_in[14];

    int Mpad = ((N + 127) / 128) * 128;

    char* ws = (char*)d_ws;
    size_t off = 0;
    auto alloc = [&](size_t bytes) {
        size_t o = off;
        off = (off + bytes + 255) & ~(size_t)255;
        return o;
    };
    int* counts = (int*)(ws + alloc((size_t)N * 4));
    int* cursor = (int*)(ws + alloc((size_t)N * 4));
    int* row_ptr = (int*)(ws + alloc((size_t)(N + 1) * 4));
    float* norm = (float*)(ws + alloc((size_t)N * 4));
    int* pre = (int*)(ws + alloc((size_t)N * 4));
    int* partials = (int*)(ws + alloc((size_t)1024 * 4));
    int* esrc = (int*)(ws + alloc((size_t)E * 4));
    u16* WT = (u16*)(ws + alloc((size_t)512 * 512 * 2));
    float* bias = (float*)(ws + alloc((size_t)512 * 4));
    u32* xf8 = (u32*)(ws + alloc((size_t)N * 64 * 4));
    u16* Zin = (u16*)(ws + alloc((size_t)Mpad * 512 * 2));
    u16* Zout = (u16*)(ws + alloc((size_t)Mpad * 512 * 2));
    (void)ws_size;

    int NB = (N + 1023) / 1024;
    int nodesPerRange = (N + 7) / 8;

    hipMemsetAsync(counts, 0, (size_t)N * 4, stream);
    {
        const int cChunks = 32;
        int epc = (((E + cChunks - 1) / cChunks) + 1023) & ~1023;
        count_kernel<<<cChunks * 8, 256, (size_t)nodesPerRange * 4, stream>>>(
            ei + E, E, counts, nodesPerRange, epc, N);
    }
    scanA_kernel<<<NB, 1024, 0, stream>>>(counts, pre, partials, N);
    scanB_kernel<<<1, 1024, 0, stream>>>(partials, NB);
    scanC_kernel<<<(N + 255) / 256, 256, 0, stream>>>(counts, pre, partials, row_ptr,
                                                      cursor, norm, N, E);
    convert_kernel<<<(N * 64 + 255) / 256, 256, 0, stream>>>(x, hx, norm, (u32*)Zin, xf8, N);
    prep_kernel<<<1024, 256, 0, stream>>>(Wrx, Wrh, Wux, Wuh, Wcx, Wch,
                                          brx, brh, bux, buh, bcx, bch, WT, bias);
    {
        const int fChunks = 256;
        int epc = (((E + fChunks - 1) / fChunks) + 1023) & ~1023;
        fill_kernel<<<fChunks * 8, 256, 0, stream>>>(ei, ei + E, E, cursor, esrc,
                                                     nodesPerRange, epc);
    }
    agg_kernel<<<(N + 3) / 4, 256, 0, stream>>>(row_ptr, esrc, norm, xf8, (u32*)Zin, N);
    dim3 ggrid(Mpad / 128, 4);
    gemm_kernel<<<ggrid, 256, 0, stream>>>(Zin, WT, Zout, Mpad);
    epilogue_kernel<<<((size_t)N * 64 + 255) / 256, 256, 0, stream>>>((const u32*)Zout, bias, hx,
                                                                      (float*)d_out, N);
}

// Round 9
// 357.194 us; speedup vs baseline: 1.0286x; 1.0286x over previous
//
#include <hip/hip_runtime.h>
#include <hip/hip_bf16.h>

// GConvGRU (ChebConv K=2), fp32 in/out; bf16 MFMA GEMM; fp8 gather path.
// Zin row K-layout: [x | hx | px | ph] (512 bf16 = 1 KB/node).
// xf8[n]: 256 fp8 bytes = concat(x[n],hx[n]) * norm[n]  (prescaled).
// CSR build = counting sort: bucket(range-partition COO) -> count(LDS hist,
// range-local) -> scan -> fill(range-local). All edge streams XCD-local after
// bucketing so dirty esrc lines accumulate in L2 (kills 10x writeback amp).

typedef unsigned short u16;
typedef unsigned int u32;
typedef __attribute__((ext_vector_type(8))) __bf16 bf16x8;
typedef __attribute__((ext_vector_type(4))) float f32x4;
typedef __attribute__((ext_vector_type(2))) float f32x2;
typedef __attribute__((ext_vector_type(4))) int int4v;

#define F_IN 128
#define HID 128

__device__ __forceinline__ u16 f2bf(float f) {
    u32 u;
    __builtin_memcpy(&u, &f, 4);
    u = (u + 0x7fffu + ((u >> 16) & 1u)) >> 16;
    return (u16)u;
}
__device__ __forceinline__ float bflo(u32 w) {
    u32 u = w << 16;
    float f;
    __builtin_memcpy(&f, &u, 4);
    return f;
}
__device__ __forceinline__ float bfhi(u32 w) {
    u32 u = w & 0xffff0000u;
    float f;
    __builtin_memcpy(&f, &u, 4);
    return f;
}
__device__ __forceinline__ u32 packbf(float a, float b) {
    return ((u32)f2bf(b) << 16) | (u32)f2bf(a);
}
__device__ __forceinline__ float sigmoidf_(float x) {
    return 1.0f / (1.0f + __expf(-x));
}

__device__ __forceinline__ void async_copy16(void* lds, const void* gptr) {
    __builtin_amdgcn_global_load_lds(
        (__attribute__((address_space(1))) void*)gptr,
        (__attribute__((address_space(3))) void*)lds,
        16, 0, 0);
}

// ------------- 1. bucket: range-partition COO into 8 dst-range segments -------------
__global__ __launch_bounds__(256) void bucket_kernel(const int* __restrict__ src,
                                                     const int* __restrict__ dst, int E,
                                                     int* __restrict__ rangeCursor,
                                                     int2* __restrict__ bedges,
                                                     int nodesPerRange, int segCap,
                                                     int edgesPerChunk) {
    __shared__ int cnt[8], base[8], pos[8];
    if (threadIdx.x < 8) cnt[threadIdx.x] = 0;
    __syncthreads();
    int beg = blockIdx.x * edgesPerChunk;
    int end = beg + edgesPerChunk;
    if (end > E) end = E;
    unsigned npr = (unsigned)nodesPerRange;
    // pass 1: per-range counts
    for (int i = beg + (int)threadIdx.x * 4; i < end; i += 256 * 4) {
        if (i + 4 <= end) {
            int4v d4 = *(const int4v*)(dst + i);
#pragma unroll
            for (int j = 0; j < 4; ++j) {
                unsigned r = (unsigned)d4[j] / npr;
                atomicAdd(&cnt[r], 1);
            }
        } else {
            for (int j = i; j < end; ++j) atomicAdd(&cnt[(unsigned)dst[j] / npr], 1);
        }
    }
    __syncthreads();
    if (threadIdx.x < 8) {
        base[threadIdx.x] = atomicAdd(&rangeCursor[threadIdx.x], cnt[threadIdx.x]);
        pos[threadIdx.x] = 0;
    }
    __syncthreads();
    // pass 2: emit (chunk is L2-hot now)
    for (int i = beg + (int)threadIdx.x * 4; i < end; i += 256 * 4) {
        if (i + 4 <= end) {
            int4v d4 = *(const int4v*)(dst + i);
            int4v s4 = *(const int4v*)(src + i);
#pragma unroll
            for (int j = 0; j < 4; ++j) {
                int d = d4[j];
                unsigned r = (unsigned)d / npr;
                int p = atomicAdd(&pos[r], 1);
                int o = base[r] + p;
                if (o < segCap) bedges[(size_t)r * segCap + o] = make_int2(d, s4[j]);
            }
        } else {
            for (int j = i; j < end; ++j) {
                int d = dst[j];
                unsigned r = (unsigned)d / npr;
                int p = atomicAdd(&pos[r], 1);
                int o = base[r] + p;
                if (o < segCap) bedges[(size_t)r * segCap + o] = make_int2(d, src[j]);
            }
        }
    }
}

// ------------- 2. count: LDS histogram over range-local segment -------------
__global__ __launch_bounds__(256) void count2_kernel(const int2* __restrict__ bedges,
                                                     const int* __restrict__ rangeCursor,
                                                     int* __restrict__ counts,
                                                     int nodesPerRange, int segCap,
                                                     int chunksPerRange, int N) {
    extern __shared__ int hist[];
    int range = blockIdx.x & 7;
    int chunk = blockIdx.x >> 3;
    int lo = range * nodesPerRange;
    int hiN = N - lo;
    int npr = nodesPerRange < hiN ? nodesPerRange : hiN;
    for (int j = threadIdx.x; j < npr; j += 256) hist[j] = 0;
    __syncthreads();
    int cnt = rangeCursor[range];
    if (cnt > segCap) cnt = segCap;
    int per = (cnt + chunksPerRange - 1) / chunksPerRange;
    int beg = chunk * per;
    int end = beg + per;
    if (end > cnt) end = cnt;
    const int2* seg = bedges + (size_t)range * segCap;
    for (int i = beg + (int)threadIdx.x; i < end; i += 256) {
        int d = seg[i].x;
        atomicAdd(&hist[d - lo], 1);
    }
    __syncthreads();
    for (int j = threadIdx.x; j < npr; j += 256) {
        int v = hist[j];
        if (v) atomicAdd(&counts[lo + j], v);
    }
}

// ------------- 3a. block-level scan (coalesced) -------------
__global__ __launch_bounds__(1024) void scanA_kernel(const int* __restrict__ counts,
                                                     int* __restrict__ pre,
                                                     int* __restrict__ partials, int N) {
    __shared__ int buf[1024];
    int tid = threadIdx.x;
    int t = blockIdx.x * 1024 + tid;
    int v = (t < N) ? counts[t] : 0;
    buf[tid] = v;
    __syncthreads();
    for (int off = 1; off < 1024; off <<= 1) {
        int o = (tid >= off) ? buf[tid - off] : 0;
        __syncthreads();
        buf[tid] += o;
        __syncthreads();
    }
    if (t < N) pre[t] = buf[tid] - v;
    if (tid == 1023) partials[blockIdx.x] = buf[1023];
}

// ------------- 3b. scan the block totals (1 block) -------------
__global__ __launch_bounds__(1024) void scanB_kernel(int* __restrict__ partials, int NB) {
    __shared__ int buf[1024];
    int tid = threadIdx.x;
    int v = (tid < NB) ? partials[tid] : 0;
    buf[tid] = v;
    __syncthreads();
    for (int off = 1; off < 1024; off <<= 1) {
        int o = (tid >= off) ? buf[tid - off] : 0;
        __syncthreads();
        buf[tid] += o;
        __syncthreads();
    }
    if (tid < NB) partials[tid] = buf[tid] - v;
}

// ------------- 3c. combine + norm (coalesced) -------------
__global__ void scanC_kernel(const int* __restrict__ counts, const int* __restrict__ pre,
                             const int* __restrict__ partials, int* __restrict__ row_ptr,
                             int* __restrict__ cursor, float* __restrict__ norm, int N, int E) {
    int i = blockIdx.x * blockDim.x + threadIdx.x;
    if (i < N) {
        int r = pre[i] + partials[i >> 10];
        row_ptr[i] = r;
        cursor[i] = r;
        int c = counts[i];
        norm[i] = rsqrtf((float)(c > 1 ? c : 1));
    }
    if (i == 0) row_ptr[N] = E;
}

// ------------- 4. convert: x,hx -> Zin bf16 slots + prescaled fp8 rows -------------
__global__ void convert_kernel(const float* __restrict__ x, const float* __restrict__ hx,
                               const float* __restrict__ norm,
                               u32* __restrict__ zin, u32* __restrict__ xf8, int N) {
    int t = blockIdx.x * blockDim.x + threadIdx.x;
    if (t >= N * 64) return;
    int n = t >> 6, c4 = t & 63;
    float4 v;
    int zbase;
    if (c4 < 32) {
        v = ((const float4*)x)[n * 32 + c4];
        zbase = n * 256 + 2 * c4;
    } else {
        v = ((const float4*)hx)[n * 32 + (c4 - 32)];
        zbase = n * 256 + 64 + 2 * (c4 - 32);
    }
    zin[zbase] = packbf(v.x, v.y);
    zin[zbase + 1] = packbf(v.z, v.w);
    float ns = norm[n];
    u32 o = 0;
    o = (u32)__builtin_amdgcn_cvt_pk_fp8_f32(v.x * ns, v.y * ns, (int)o, false);
    o = (u32)__builtin_amdgcn_cvt_pk_fp8_f32(v.z * ns, v.w * ns, (int)o, true);
    xf8[t] = o;
}

// ------------- 5. weight prepack (fp32 -> bf16) + bias pack -------------
__global__ void prep_kernel(const float* __restrict__ Wrx, const float* __restrict__ Wrh,
                            const float* __restrict__ Wux, const float* __restrict__ Wuh,
                            const float* __restrict__ Wcx, const float* __restrict__ Wch,
                            const float* __restrict__ brx, const float* __restrict__ brh,
                            const float* __restrict__ bux, const float* __restrict__ buh,
                            const float* __restrict__ bcx, const float* __restrict__ bch,
                            u16* __restrict__ WT, float* __restrict__ bias) {
    int t = blockIdx.x * blockDim.x + threadIdx.x;  // [0, 512*512)
    int c = t >> 9, k = t & 511;
    int part = c >> 7, c0 = c & 127;
    int kpart = k >> 7;
    int kf = k & 127;
    int t01 = (kpart & 2) ? 1 : 0;
    bool isX = !(kpart & 1);
    int wi = t01 * (128 * 128) + kf * 128 + c0;
    float val = 0.0f;
    if (part == 0) val = isX ? Wrx[wi] : Wrh[wi];
    else if (part == 1) val = isX ? Wux[wi] : Wuh[wi];
    else if (part == 2) { if (isX) val = Wcx[wi]; }
    else { if (!isX) val = Wch[wi]; }
    WT[c * 512 + k] = f2bf(val);
    if (t < 512) {
        int bp = t >> 7, bc = t & 127;
        float b = 0.0f;
        if (bp == 0) b = brx[bc] + brh[bc];
        else if (bp == 1) b = bux[bc] + buh[bc];
        else if (bp == 2) b = bcx[bc];
        else b = bch[bc];
        bias[t] = b;
    }
}

// ------------- 6. fill: range-local counting-sort scatter -------------
__global__ __launch_bounds__(256) void fill2_kernel(const int2* __restrict__ bedges,
                                                    const int* __restrict__ rangeCursor,
                                                    int* __restrict__ cursor,
                                                    int* __restrict__ esrc,
                                                    int segCap, int chunksPerRange) {
    int range = blockIdx.x & 7;
    int chunk = blockIdx.x >> 3;
    int cnt = rangeCursor[range];
    if (cnt > segCap) cnt = segCap;
    int per = (cnt + chunksPerRange - 1) / chunksPerRange;
    int beg = chunk * per;
    int end = beg + per;
    if (end > cnt) end = cnt;
    const int2* seg = bedges + (size_t)range * segCap;
    for (int i = beg + (int)threadIdx.x; i < end; i += 256) {
        int2 e = seg[i];
        int slot = atomicAdd(&cursor[e.x], 1);
        esrc[slot] = e.y;
    }
}

// ------------- 7. wave-per-node fp8 gather-aggregate, 8 edges/iter -------------
__global__ __launch_bounds__(256) void agg_kernel(const int* __restrict__ row_ptr,
                                                  const int* __restrict__ esrc,
                                                  const float* __restrict__ norm,
                                                  const u32* __restrict__ xf8,
                                                  u32* __restrict__ zin, int N) {
    int node = blockIdx.x * 4 + (threadIdx.x >> 6);
    int lane = threadIdx.x & 63;
    if (node >= N) return;
    int q = lane >> 4;
    int li = lane & 15;
    int beg = row_ptr[node], end = row_ptr[node + 1];
    const uint4* z4 = (const uint4*)xf8;
    f32x2 acc[8];
#pragma unroll
    for (int i = 0; i < 8; ++i) acc[i] = (f32x2){0.f, 0.f};

    int nE = end - beg;
    int mainEnd = beg + (nE & ~7);
    int e = beg;
    if (e < mainEnd) {
        int sA = esrc[e + q];
        int sB = esrc[e + q + 4];
        for (;;) {
            uint4 vA = z4[(size_t)sA * 16 + li];
            uint4 vB = z4[(size_t)sB * 16 + li];
            e += 8;
            bool more = e < mainEnd;
            int tA = 0, tB = 0;
            if (more) {
                tA = esrc[e + q];
                tB = esrc[e + q + 4];
            }
#pragma unroll
            for (int i = 0; i < 4; ++i) {
                u32 w = (i == 0) ? vA.x : (i == 1) ? vA.y : (i == 2) ? vA.z : vA.w;
                acc[2 * i] += (f32x2)__builtin_amdgcn_cvt_pk_f32_fp8((int)w, false);
                acc[2 * i + 1] += (f32x2)__builtin_amdgcn_cvt_pk_f32_fp8((int)w, true);
            }
#pragma unroll
            for (int i = 0; i < 4; ++i) {
                u32 w = (i == 0) ? vB.x : (i == 1) ? vB.y : (i == 2) ? vB.z : vB.w;
                acc[2 * i] += (f32x2)__builtin_amdgcn_cvt_pk_f32_fp8((int)w, false);
                acc[2 * i + 1] += (f32x2)__builtin_amdgcn_cvt_pk_f32_fp8((int)w, true);
            }
            if (!more) break;
            sA = tA;
            sB = tB;
        }
    }
    for (int t = mainEnd + q; t < end; t += 4) {
        int s = esrc[t];
        uint4 v = z4[(size_t)s * 16 + li];
#pragma unroll
        for (int i = 0; i < 4; ++i) {
            u32 w = (i == 0) ? v.x : (i == 1) ? v.y : (i == 2) ? v.z : v.w;
            acc[2 * i] += (f32x2)__builtin_amdgcn_cvt_pk_f32_fp8((int)w, false);
            acc[2 * i + 1] += (f32x2)__builtin_amdgcn_cvt_pk_f32_fp8((int)w, true);
        }
    }
#pragma unroll
    for (int i = 0; i < 8; ++i) {
        acc[i].x += __shfl_xor(acc[i].x, 16);
        acc[i].y += __shfl_xor(acc[i].y, 16);
        acc[i].x += __shfl_xor(acc[i].x, 32);
        acc[i].y += __shfl_xor(acc[i].y, 32);
    }
    if (lane < 16) {
        float nn = -norm[node];
        uint4 o0, o1;
        o0.x = packbf(acc[0].x * nn, acc[0].y * nn);
        o0.y = packbf(acc[1].x * nn, acc[1].y * nn);
        o0.z = packbf(acc[2].x * nn, acc[2].y * nn);
        o0.w = packbf(acc[3].x * nn, acc[3].y * nn);
        o1.x = packbf(acc[4].x * nn, acc[4].y * nn);
        o1.y = packbf(acc[5].x * nn, acc[5].y * nn);
        o1.z = packbf(acc[6].x * nn, acc[6].y * nn);
        o1.w = packbf(acc[7].x * nn, acc[7].y * nn);
        uint4* dst4 = (uint4*)zin + (size_t)node * 64 + 32 + li * 2;
        dst4[0] = o0;
        dst4[1] = o1;
    }
}

// ------------- 8. MFMA GEMM: Z[M,512] = A[M,512] * B^T (B stored [col][k]) -------------
__global__ __launch_bounds__(256) void gemm_kernel(const u16* __restrict__ A,
                                                   const u16* __restrict__ B,
                                                   u16* __restrict__ C, int M) {
    __shared__ __align__(16) __bf16 As[128 * 32];
    __shared__ __align__(16) __bf16 Bs[128 * 32];
    int tid = threadIdx.x;
    int wave = tid >> 6, lane = tid & 63;
    int m0 = blockIdx.x * 128;
    int n0 = blockIdx.y * 128;
    int wm = wave & 1, wn = wave >> 1;
    int quad = lane >> 4, l15 = lane & 15;

    f32x4 acc[4][4];
#pragma unroll
    for (int mi = 0; mi < 4; ++mi)
#pragma unroll
        for (int ni = 0; ni < 4; ++ni) acc[mi][ni] = (f32x4){0.f, 0.f, 0.f, 0.f};

    for (int k0 = 0; k0 < 512; k0 += 32) {
        __syncthreads();
#pragma unroll
        for (int j = 0; j < 2; ++j) {
            int chunk = wave * 2 + j;
            int fl = chunk * 512 + lane * 8;
            int row = fl >> 5;
            int col = fl & 31;
            async_copy16(&As[chunk * 512], A + (size_t)(m0 + row) * 512 + k0 + col);
            async_copy16(&Bs[chunk * 512], B + (size_t)(n0 + row) * 512 + k0 + col);
        }
        __syncthreads();
        bf16x8 af[4], bfr[4];
#pragma unroll
        for (int mi = 0; mi < 4; ++mi)
            af[mi] = *(const bf16x8*)&As[(wm * 64 + mi * 16 + l15) * 32 + quad * 8];
#pragma unroll
        for (int ni = 0; ni < 4; ++ni)
            bfr[ni] = *(const bf16x8*)&Bs[(wn * 64 + ni * 16 + l15) * 32 + quad * 8];
#pragma unroll
        for (int mi = 0; mi < 4; ++mi)
#pragma unroll
            for (int ni = 0; ni < 4; ++ni)
                acc[mi][ni] = __builtin_amdgcn_mfma_f32_16x16x32_bf16(af[mi], bfr[ni],
                                                                      acc[mi][ni], 0, 0, 0);
    }
#pragma unroll
    for (int mi = 0; mi < 4; ++mi)
#pragma unroll
        for (int ni = 0; ni < 4; ++ni)
#pragma unroll
            for (int r = 0; r < 4; ++r) {
                int row = m0 + wm * 64 + mi * 16 + quad * 4 + r;
                int col = n0 + wn * 64 + ni * 16 + l15;
                C[(size_t)row * 512 + col] = f2bf(acc[mi][ni][r]);
            }
}

// ------------- 9. gate epilogue (fp32 out), 2 features/thread -------------
__global__ void epilogue_kernel(const u32* __restrict__ Z, const float* __restrict__ bias,
                                const float* __restrict__ hx, float* __restrict__ out, int N) {
    int t = blockIdx.x * blockDim.x + threadIdx.x;
    if (t >= N * 64) return;
    int n = t >> 6, l = t & 63;
    const u32* z = Z + (size_t)n * 256;
    const float2* b2 = (const float2*)bias;
    u32 wr = z[l], wu = z[64 + l], wcx = z[128 + l], wch = z[192 + l];
    float2 br = b2[l], bu = b2[64 + l], bcx = b2[128 + l], bch = b2[192 + l];
    float2 h = ((const float2*)hx)[t];
    float r0 = sigmoidf_(bflo(wr) + br.x);
    float r1 = sigmoidf_(bfhi(wr) + br.y);
    float u0 = sigmoidf_(bflo(wu) + bu.x);
    float u1 = sigmoidf_(bfhi(wu) + bu.y);
    float c0 = sigmoidf_((bflo(wcx) + bcx.x) + (bflo(wch) + bch.x) * r0);
    float c1 = sigmoidf_((bfhi(wcx) + bcx.y) + (bfhi(wch) + bch.y) * r1);
    float2 o;
    o.x = u0 * h.x + (1.0f - u0) * c0;
    o.y = u1 * h.y + (1.0f - u1) * c1;
    ((float2*)out)[t] = o;
}

extern "C" void kernel_launch(void* const* d_in, const int* in_sizes, int n_in,
                              void* d_out, int out_size, void* d_ws, size_t ws_size,
                              hipStream_t stream) {
    const int* ei = (const int*)d_in[0];
    int E = in_sizes[0] / 2;
    const float* x = (const float*)d_in[1];
    const float* hx = (const float*)d_in[2];
    int N = in_sizes[1] / F_IN;
    const float* Wrx = (const float*)d_in[3];
    const float* brx = (const float*)d_in[4];
    const float* Wrh = (const float*)d_in[5];
    const float* brh = (const float*)d_in[6];
    const float* Wux = (const float*)d_in[7];
    const float* bux = (const float*)d_in[8];
    const float* Wuh = (const float*)d_in[9];
    const float* buh = (const float*)d_in[10];
    const float* Wcx = (const float*)d_in[11];
    const float* bcx = (const float*)d_in[12];
    const float* Wch = (const float*)d_in[13];
    const float* bch = (const float*)d_in[14];

    int Mpad = ((N + 127) / 128) * 128;

    char* ws = (char*)d_ws;
    size_t off = 0;
    auto alloc = [&](size_t bytes) {
        size_t o = off;
        off = (off + bytes + 255) & ~(size_t)255;
        return o;
    };
    int* rangeCursor = (int*)(ws + alloc(256));          // 8 ints (padded)
    int* counts = (int*)(ws + alloc((size_t)N * 4));     // contiguous with rangeCursor
    int* cursor = (int*)(ws + alloc((size_t)N * 4));
    int* row_ptr = (int*)(ws + alloc((size_t)(N + 1) * 4));
    float* norm = (float*)(ws + alloc((size_t)N * 4));
    int* pre = (int*)(ws + alloc((size_t)N * 4));
    int* partials = (int*)(ws + alloc((size_t)1024 * 4));
    int* esrc = (int*)(ws + alloc((size_t)E * 4));
    int segCap = E / 8 + 32768;
    int2* bedges = (int2*)(ws + alloc((size_t)segCap * 8 * 8));
    u16* WT = (u16*)(ws + alloc((size_t)512 * 512 * 2));
    float* bias = (float*)(ws + alloc((size_t)512 * 4));
    u32* xf8 = (u32*)(ws + alloc((size_t)N * 64 * 4));
    u16* Zin = (u16*)(ws + alloc((size_t)Mpad * 512 * 2));
    u16* Zout = (u16*)(ws + alloc((size_t)Mpad * 512 * 2));
    (void)ws_size;

    int NB = (N + 1023) / 1024;
    int nodesPerRange = (N + 7) / 8;

    // zero rangeCursor (256 B pad) + counts in one memset (they are adjacent)
    hipMemsetAsync(rangeCursor, 0, 256 + (size_t)N * 4, stream);
    {
        const int bChunks = 256;
        int epc = (((E + bChunks - 1) / bChunks) + 3) & ~3;
        bucket_kernel<<<bChunks, 256, 0, stream>>>(ei, ei + E, E, rangeCursor, bedges,
                                                   nodesPerRange, segCap, epc);
    }
    count2_kernel<<<32 * 8, 256, (size_t)nodesPerRange * 4, stream>>>(
        bedges, rangeCursor, counts, nodesPerRange, segCap, 32, N);
    scanA_kernel<<<NB, 1024, 0, stream>>>(counts, pre, partials, N);
    scanB_kernel<<<1, 1024, 0, stream>>>(partials, NB);
    scanC_kernel<<<(N + 255) / 256, 256, 0, stream>>>(counts, pre, partials, row_ptr,
                                                      cursor, norm, N, E);
    convert_kernel<<<(N * 64 + 255) / 256, 256, 0, stream>>>(x, hx, norm, (u32*)Zin, xf8, N);
    prep_kernel<<<1024, 256, 0, stream>>>(Wrx, Wrh, Wux, Wuh, Wcx, Wch,
                                          brx, brh, bux, buh, bcx, bch, WT, bias);
    fill2_kernel<<<32 * 8, 256, 0, stream>>>(bedges, rangeCursor, cursor, esrc, segCap, 32);
    agg_kernel<<<(N + 3) / 4, 256, 0, stream>>>(row_ptr, esrc, norm, xf8, (u32*)Zin, N);
    dim3 ggrid(Mpad / 128, 4);
    gemm_kernel<<<ggrid, 256, 0, stream>>>(Zin, WT, Zout, Mpad);
    epilogue_kernel<<<((size_t)N * 64 + 255) / 256, 256, 0, stream>>>((const u32*)Zout, bias, hx,
                                                                      (float*)d_out, N);
}

// Round 10
// 285.661 us; speedup vs baseline: 1.2862x; 1.2504x over previous
//
#include <hip/hip_runtime.h>
#include <hip/hip_bf16.h>

// GConvGRU (ChebConv K=2), fp32 in/out; bf16 MFMA GEMM; fp8 gather path.
// Zin row K-layout: [x | hx | px | ph] (512 bf16 = 1 KB/node).
// xf8[n]: 256 fp8 bytes = concat(x[n],hx[n]) * norm[n] (prescaled).
// CSR build = counting sort with BLOCK-PRIVATE scatter windows:
//   bucket: COO -> 98 segments of 512 nodes (coalesced run writes)
//   csr:    per-segment fused hist+scan+row_ptr+norm+fill (private esrc window
//           per block -> no cross-XCD line sharing -> no writeback amplification)

typedef unsigned short u16;
typedef unsigned int u32;
typedef __attribute__((ext_vector_type(8))) __bf16 bf16x8;
typedef __attribute__((ext_vector_type(4))) float f32x4;
typedef __attribute__((ext_vector_type(2))) float f32x2;
typedef __attribute__((ext_vector_type(4))) int int4v;

#define F_IN 128
#define HID 128
#define NPS 512           // nodes per segment (power of 2: r = d >> 9)
#define NPS_SHIFT 9

__device__ __forceinline__ u16 f2bf(float f) {
    u32 u;
    __builtin_memcpy(&u, &f, 4);
    u = (u + 0x7fffu + ((u >> 16) & 1u)) >> 16;
    return (u16)u;
}
__device__ __forceinline__ float bflo(u32 w) {
    u32 u = w << 16;
    float f;
    __builtin_memcpy(&f, &u, 4);
    return f;
}
__device__ __forceinline__ float bfhi(u32 w) {
    u32 u = w & 0xffff0000u;
    float f;
    __builtin_memcpy(&f, &u, 4);
    return f;
}
__device__ __forceinline__ u32 packbf(float a, float b) {
    return ((u32)f2bf(b) << 16) | (u32)f2bf(a);
}
__device__ __forceinline__ float sigmoidf_(float x) {
    return 1.0f / (1.0f + __expf(-x));
}

__device__ __forceinline__ void async_copy16(void* lds, const void* gptr) {
    __builtin_amdgcn_global_load_lds(
        (__attribute__((address_space(1))) void*)gptr,
        (__attribute__((address_space(3))) void*)lds,
        16, 0, 0);
}

// ------------- 1. bucket: partition COO into NSEG segments of NPS nodes -------------
__global__ __launch_bounds__(256) void bucket_kernel(const int* __restrict__ src,
                                                     const int* __restrict__ dst, int E,
                                                     int* __restrict__ segCount,
                                                     int2* __restrict__ bedges,
                                                     int segCap, int edgesPerChunk,
                                                     int NSEG) {
    __shared__ int cnt[128], base[128], pos[128];
    for (int i = threadIdx.x; i < NSEG; i += 256) cnt[i] = 0;
    __syncthreads();
    int beg = blockIdx.x * edgesPerChunk;
    int end = beg + edgesPerChunk;
    if (end > E) end = E;
    // pass 1: per-segment counts
    for (int i = beg + (int)threadIdx.x * 4; i < end; i += 256 * 4) {
        if (i + 4 <= end) {
            int4v d4 = *(const int4v*)(dst + i);
#pragma unroll
            for (int j = 0; j < 4; ++j) atomicAdd(&cnt[(unsigned)d4[j] >> NPS_SHIFT], 1);
        } else {
            for (int j = i; j < end; ++j) atomicAdd(&cnt[(unsigned)dst[j] >> NPS_SHIFT], 1);
        }
    }
    __syncthreads();
    for (int i = threadIdx.x; i < NSEG; i += 256) {
        base[i] = atomicAdd(&segCount[i], cnt[i]);
        pos[i] = 0;
    }
    __syncthreads();
    // pass 2: emit (chunk is cache-hot from pass 1)
    for (int i = beg + (int)threadIdx.x * 4; i < end; i += 256 * 4) {
        if (i + 4 <= end) {
            int4v d4 = *(const int4v*)(dst + i);
            int4v s4 = *(const int4v*)(src + i);
#pragma unroll
            for (int j = 0; j < 4; ++j) {
                int d = d4[j];
                unsigned r = (unsigned)d >> NPS_SHIFT;
                int p = atomicAdd(&pos[r], 1);
                int o = base[r] + p;
                if (o < segCap) bedges[(size_t)r * segCap + o] = make_int2(d, s4[j]);
            }
        } else {
            for (int j = i; j < end; ++j) {
                int d = dst[j];
                unsigned r = (unsigned)d >> NPS_SHIFT;
                int p = atomicAdd(&pos[r], 1);
                int o = base[r] + p;
                if (o < segCap) bedges[(size_t)r * segCap + o] = make_int2(d, src[j]);
            }
        }
    }
}

// ------------- 2. fused per-segment CSR: hist + scan + row_ptr + norm + fill -------------
// One block per segment. esrc window [segBase, segBase+cnt) is block-private.
__global__ __launch_bounds__(1024) void csr_kernel(const int2* __restrict__ bedges,
                                                   const int* __restrict__ segCount,
                                                   int* __restrict__ row_ptr,
                                                   float* __restrict__ norm,
                                                   int* __restrict__ esrc,
                                                   int segCap, int N, int E, int NSEG) {
    __shared__ int hist[NPS];
    __shared__ int sseg[128];
    __shared__ int segBaseSh;
    int seg = blockIdx.x;
    int tid = threadIdx.x;
    int lo = seg << NPS_SHIFT;
    int npr = N - lo;
    if (npr > NPS) npr = NPS;

    // mini-scan of segCount[0..NSEG) for segBase
    if (tid < 128) sseg[tid] = (tid < NSEG) ? segCount[tid] : 0;
    __syncthreads();
    for (int off = 1; off < 128; off <<= 1) {
        int v = 0;
        if (tid < 128 && tid >= off) v = sseg[tid - off];
        __syncthreads();
        if (tid < 128) sseg[tid] += v;
        __syncthreads();
    }
    if (tid == 0) segBaseSh = (seg == 0) ? 0 : sseg[seg - 1];
    if (tid < NPS) hist[tid] = 0;
    __syncthreads();

    int cnt = segCount[seg];
    if (cnt > segCap) cnt = segCap;
    const int2* segp = bedges + (size_t)seg * segCap;

    // pass 1: histogram dst
    for (int i = tid; i < cnt; i += 1024) atomicAdd(&hist[segp[i].x - lo], 1);
    __syncthreads();
    int myCount = (tid < NPS) ? hist[tid] : 0;
    __syncthreads();
    // inclusive scan of hist
    for (int off = 1; off < NPS; off <<= 1) {
        int v = 0;
        if (tid < NPS && tid >= off) v = hist[tid - off];
        __syncthreads();
        if (tid < NPS) hist[tid] += v;
        __syncthreads();
    }
    int segBase = segBaseSh;
    if (tid < npr) {
        int excl = hist[tid] - myCount;
        row_ptr[lo + tid] = segBase + excl;
        norm[lo + tid] = rsqrtf((float)(myCount > 1 ? myCount : 1));
    }
    __syncthreads();
    if (tid < NPS) hist[tid] = segBase + hist[tid] - myCount;  // global cursors
    __syncthreads();
    // pass 2: fill (private window)
    for (int i = tid; i < cnt; i += 1024) {
        int2 e = segp[i];
        int slot = atomicAdd(&hist[e.x - lo], 1);
        esrc[slot] = e.y;
    }
    if (seg == NSEG - 1 && tid == 0) row_ptr[N] = E;
}

// ------------- 3. convert: x,hx -> Zin bf16 slots + prescaled fp8 rows -------------
__global__ void convert_kernel(const float* __restrict__ x, const float* __restrict__ hx,
                               const float* __restrict__ norm,
                               u32* __restrict__ zin, u32* __restrict__ xf8, int N) {
    int t = blockIdx.x * blockDim.x + threadIdx.x;
    if (t >= N * 64) return;
    int n = t >> 6, c4 = t & 63;
    float4 v;
    int zbase;
    if (c4 < 32) {
        v = ((const float4*)x)[n * 32 + c4];
        zbase = n * 256 + 2 * c4;
    } else {
        v = ((const float4*)hx)[n * 32 + (c4 - 32)];
        zbase = n * 256 + 64 + 2 * (c4 - 32);
    }
    zin[zbase] = packbf(v.x, v.y);
    zin[zbase + 1] = packbf(v.z, v.w);
    float ns = norm[n];
    u32 o = 0;
    o = (u32)__builtin_amdgcn_cvt_pk_fp8_f32(v.x * ns, v.y * ns, (int)o, false);
    o = (u32)__builtin_amdgcn_cvt_pk_fp8_f32(v.z * ns, v.w * ns, (int)o, true);
    xf8[t] = o;
}

// ------------- 4. weight prepack (fp32 -> bf16) + bias pack -------------
__global__ void prep_kernel(const float* __restrict__ Wrx, const float* __restrict__ Wrh,
                            const float* __restrict__ Wux, const float* __restrict__ Wuh,
                            const float* __restrict__ Wcx, const float* __restrict__ Wch,
                            const float* __restrict__ brx, const float* __restrict__ brh,
                            const float* __restrict__ bux, const float* __restrict__ buh,
                            const float* __restrict__ bcx, const float* __restrict__ bch,
                            u16* __restrict__ WT, float* __restrict__ bias) {
    int t = blockIdx.x * blockDim.x + threadIdx.x;  // [0, 512*512)
    int c = t >> 9, k = t & 511;
    int part = c >> 7, c0 = c & 127;
    int kpart = k >> 7;
    int kf = k & 127;
    int t01 = (kpart & 2) ? 1 : 0;
    bool isX = !(kpart & 1);
    int wi = t01 * (128 * 128) + kf * 128 + c0;
    float val = 0.0f;
    if (part == 0) val = isX ? Wrx[wi] : Wrh[wi];
    else if (part == 1) val = isX ? Wux[wi] : Wuh[wi];
    else if (part == 2) { if (isX) val = Wcx[wi]; }
    else { if (!isX) val = Wch[wi]; }
    WT[c * 512 + k] = f2bf(val);
    if (t < 512) {
        int bp = t >> 7, bc = t & 127;
        float b = 0.0f;
        if (bp == 0) b = brx[bc] + brh[bc];
        else if (bp == 1) b = bux[bc] + buh[bc];
        else if (bp == 2) b = bcx[bc];
        else b = bch[bc];
        bias[t] = b;
    }
}

// ------------- 5. wave-per-node fp8 gather-aggregate, 8 edges/iter -------------
__global__ __launch_bounds__(256) void agg_kernel(const int* __restrict__ row_ptr,
                                                  const int* __restrict__ esrc,
                                                  const float* __restrict__ norm,
                                                  const u32* __restrict__ xf8,
                                                  u32* __restrict__ zin, int N) {
    int node = blockIdx.x * 4 + (threadIdx.x >> 6);
    int lane = threadIdx.x & 63;
    if (node >= N) return;
    int q = lane >> 4;
    int li = lane & 15;
    int beg = row_ptr[node], end = row_ptr[node + 1];
    const uint4* z4 = (const uint4*)xf8;
    f32x2 acc[8];
#pragma unroll
    for (int i = 0; i < 8; ++i) acc[i] = (f32x2){0.f, 0.f};

    int nE = end - beg;
    int mainEnd = beg + (nE & ~7);
    int e = beg;
    if (e < mainEnd) {
        int sA = esrc[e + q];
        int sB = esrc[e + q + 4];
        for (;;) {
            uint4 vA = z4[(size_t)sA * 16 + li];
            uint4 vB = z4[(size_t)sB * 16 + li];
            e += 8;
            bool more = e < mainEnd;
            int tA = 0, tB = 0;
            if (more) {
                tA = esrc[e + q];
                tB = esrc[e + q + 4];
            }
#pragma unroll
            for (int i = 0; i < 4; ++i) {
                u32 w = (i == 0) ? vA.x : (i == 1) ? vA.y : (i == 2) ? vA.z : vA.w;
                acc[2 * i] += (f32x2)__builtin_amdgcn_cvt_pk_f32_fp8((int)w, false);
                acc[2 * i + 1] += (f32x2)__builtin_amdgcn_cvt_pk_f32_fp8((int)w, true);
            }
#pragma unroll
            for (int i = 0; i < 4; ++i) {
                u32 w = (i == 0) ? vB.x : (i == 1) ? vB.y : (i == 2) ? vB.z : vB.w;
                acc[2 * i] += (f32x2)__builtin_amdgcn_cvt_pk_f32_fp8((int)w, false);
                acc[2 * i + 1] += (f32x2)__builtin_amdgcn_cvt_pk_f32_fp8((int)w, true);
            }
            if (!more) break;
            sA = tA;
            sB = tB;
        }
    }
    for (int t = mainEnd + q; t < end; t += 4) {
        int s = esrc[t];
        uint4 v = z4[(size_t)s * 16 + li];
#pragma unroll
        for (int i = 0; i < 4; ++i) {
            u32 w = (i == 0) ? v.x : (i == 1) ? v.y : (i == 2) ? v.z : v.w;
            acc[2 * i] += (f32x2)__builtin_amdgcn_cvt_pk_f32_fp8((int)w, false);
            acc[2 * i + 1] += (f32x2)__builtin_amdgcn_cvt_pk_f32_fp8((int)w, true);
        }
    }
#pragma unroll
    for (int i = 0; i < 8; ++i) {
        acc[i].x += __shfl_xor(acc[i].x, 16);
        acc[i].y += __shfl_xor(acc[i].y, 16);
        acc[i].x += __shfl_xor(acc[i].x, 32);
        acc[i].y += __shfl_xor(acc[i].y, 32);
    }
    if (lane < 16) {
        float nn = -norm[node];
        uint4 o0, o1;
        o0.x = packbf(acc[0].x * nn, acc[0].y * nn);
        o0.y = packbf(acc[1].x * nn, acc[1].y * nn);
        o0.z = packbf(acc[2].x * nn, acc[2].y * nn);
        o0.w = packbf(acc[3].x * nn, acc[3].y * nn);
        o1.x = packbf(acc[4].x * nn, acc[4].y * nn);
        o1.y = packbf(acc[5].x * nn, acc[5].y * nn);
        o1.z = packbf(acc[6].x * nn, acc[6].y * nn);
        o1.w = packbf(acc[7].x * nn, acc[7].y * nn);
        uint4* dst4 = (uint4*)zin + (size_t)node * 64 + 32 + li * 2;
        dst4[0] = o0;
        dst4[1] = o1;
    }
}

// ------------- 6. MFMA GEMM: Z[M,512] = A[M,512] * B^T (B stored [col][k]) -------------
__global__ __launch_bounds__(256) void gemm_kernel(const u16* __restrict__ A,
                                                   const u16* __restrict__ B,
                                                   u16* __restrict__ C, int M) {
    __shared__ __align__(16) __bf16 As[128 * 32];
    __shared__ __align__(16) __bf16 Bs[128 * 32];
    int tid = threadIdx.x;
    int wave = tid >> 6, lane = tid & 63;
    int m0 = blockIdx.x * 128;
    int n0 = blockIdx.y * 128;
    int wm = wave & 1, wn = wave >> 1;
    int quad = lane >> 4, l15 = lane & 15;

    f32x4 acc[4][4];
#pragma unroll
    for (int mi = 0; mi < 4; ++mi)
#pragma unroll
        for (int ni = 0; ni < 4; ++ni) acc[mi][ni] = (f32x4){0.f, 0.f, 0.f, 0.f};

    for (int k0 = 0; k0 < 512; k0 += 32) {
        __syncthreads();
#pragma unroll
        for (int j = 0; j < 2; ++j) {
            int chunk = wave * 2 + j;
            int fl = chunk * 512 + lane * 8;
            int row = fl >> 5;
            int col = fl & 31;
            async_copy16(&As[chunk * 512], A + (size_t)(m0 + row) * 512 + k0 + col);
            async_copy16(&Bs[chunk * 512], B + (size_t)(n0 + row) * 512 + k0 + col);
        }
        __syncthreads();
        bf16x8 af[4], bfr[4];
#pragma unroll
        for (int mi = 0; mi < 4; ++mi)
            af[mi] = *(const bf16x8*)&As[(wm * 64 + mi * 16 + l15) * 32 + quad * 8];
#pragma unroll
        for (int ni = 0; ni < 4; ++ni)
            bfr[ni] = *(const bf16x8*)&Bs[(wn * 64 + ni * 16 + l15) * 32 + quad * 8];
#pragma unroll
        for (int mi = 0; mi < 4; ++mi)
#pragma unroll
            for (int ni = 0; ni < 4; ++ni)
                acc[mi][ni] = __builtin_amdgcn_mfma_f32_16x16x32_bf16(af[mi], bfr[ni],
                                                                      acc[mi][ni], 0, 0, 0);
    }
#pragma unroll
    for (int mi = 0; mi < 4; ++mi)
#pragma unroll
        for (int ni = 0; ni < 4; ++ni)
#pragma unroll
            for (int r = 0; r < 4; ++r) {
                int row = m0 + wm * 64 + mi * 16 + quad * 4 + r;
                int col = n0 + wn * 64 + ni * 16 + l15;
                C[(size_t)row * 512 + col] = f2bf(acc[mi][ni][r]);
            }
}

// ------------- 7. gate epilogue (fp32 out), 2 features/thread -------------
__global__ void epilogue_kernel(const u32* __restrict__ Z, const float* __restrict__ bias,
                                const float* __restrict__ hx, float* __restrict__ out, int N) {
    int t = blockIdx.x * blockDim.x + threadIdx.x;
    if (t >= N * 64) return;
    int n = t >> 6, l = t & 63;
    const u32* z = Z + (size_t)n * 256;
    const float2* b2 = (const float2*)bias;
    u32 wr = z[l], wu = z[64 + l], wcx = z[128 + l], wch = z[192 + l];
    float2 br = b2[l], bu = b2[64 + l], bcx = b2[128 + l], bch = b2[192 + l];
    float2 h = ((const float2*)hx)[t];
    float r0 = sigmoidf_(bflo(wr) + br.x);
    float r1 = sigmoidf_(bfhi(wr) + br.y);
    float u0 = sigmoidf_(bflo(wu) + bu.x);
    float u1 = sigmoidf_(bfhi(wu) + bu.y);
    float c0 = sigmoidf_((bflo(wcx) + bcx.x) + (bflo(wch) + bch.x) * r0);
    float c1 = sigmoidf_((bfhi(wcx) + bcx.y) + (bfhi(wch) + bch.y) * r1);
    float2 o;
    o.x = u0 * h.x + (1.0f - u0) * c0;
    o.y = u1 * h.y + (1.0f - u1) * c1;
    ((float2*)out)[t] = o;
}

extern "C" void kernel_launch(void* const* d_in, const int* in_sizes, int n_in,
                              void* d_out, int out_size, void* d_ws, size_t ws_size,
                              hipStream_t stream) {
    const int* ei = (const int*)d_in[0];
    int E = in_sizes[0] / 2;
    const float* x = (const float*)d_in[1];
    const float* hx = (const float*)d_in[2];
    int N = in_sizes[1] / F_IN;
    const float* Wrx = (const float*)d_in[3];
    const float* brx = (const float*)d_in[4];
    const float* Wrh = (const float*)d_in[5];
    const float* brh = (const float*)d_in[6];
    const float* Wux = (const float*)d_in[7];
    const float* bux = (const float*)d_in[8];
    const float* Wuh = (const float*)d_in[9];
    const float* buh = (const float*)d_in[10];
    const float* Wcx = (const float*)d_in[11];
    const float* bcx = (const float*)d_in[12];
    const float* Wch = (const float*)d_in[13];
    const float* bch = (const float*)d_in[14];

    int Mpad = ((N + 127) / 128) * 128;
    int NSEG = (N + NPS - 1) / NPS;          // 98 for N=50000
    int segCap = E / NSEG + 2048;            // ~16σ slack over mean

    char* ws = (char*)d_ws;
    size_t off = 0;
    auto alloc = [&](size_t bytes) {
        size_t o = off;
        off = (off + bytes + 255) & ~(size_t)255;
        return o;
    };
    int* segCount = (int*)(ws + alloc(512));
    int* row_ptr = (int*)(ws + alloc((size_t)(N + 1) * 4));
    float* norm = (float*)(ws + alloc((size_t)N * 4));
    int* esrc = (int*)(ws + alloc((size_t)E * 4));
    int2* bedges = (int2*)(ws + alloc((size_t)NSEG * segCap * 8));
    u16* WT = (u16*)(ws + alloc((size_t)512 * 512 * 2));
    float* bias = (float*)(ws + alloc((size_t)512 * 4));
    u32* xf8 = (u32*)(ws + alloc((size_t)N * 64 * 4));
    u16* Zin = (u16*)(ws + alloc((size_t)Mpad * 512 * 2));
    u16* Zout = (u16*)(ws + alloc((size_t)Mpad * 512 * 2));
    (void)ws_size;

    hipMemsetAsync(segCount, 0, 512, stream);
    {
        const int bChunks = 256;
        int epc = (((E + bChunks - 1) / bChunks) + 3) & ~3;
        bucket_kernel<<<bChunks, 256, 0, stream>>>(ei, ei + E, E, segCount, bedges,
                                                   segCap, epc, NSEG);
    }
    csr_kernel<<<NSEG, 1024, 0, stream>>>(bedges, segCount, row_ptr, norm, esrc,
                                          segCap, N, E, NSEG);
    convert_kernel<<<(N * 64 + 255) / 256, 256, 0, stream>>>(x, hx, norm, (u32*)Zin, xf8, N);
    prep_kernel<<<1024, 256, 0, stream>>>(Wrx, Wrh, Wux, Wuh, Wcx, Wch,
                                          brx, brh, bux, buh, bcx, bch, WT, bias);
    agg_kernel<<<(N + 3) / 4, 256, 0, stream>>>(row_ptr, esrc, norm, xf8, (u32*)Zin, N);
    dim3 ggrid(Mpad / 128, 4);
    gemm_kernel<<<ggrid, 256, 0, stream>>>(Zin, WT, Zout, Mpad);
    epilogue_kernel<<<((size_t)N * 64 + 255) / 256, 256, 0, stream>>>((const u32*)Zout, bias, hx,
                                                                      (float*)d_out, N);
}